// Round 5
// baseline (191.277 us; speedup 1.0000x reference)
//
#include <hip/hip_runtime.h>
#include <hip/hip_bf16.h>

#define NROWS  8192
#define DIM    256
#define NCLASS 512
#define MARGIN 0.3f

using bf16x8 = __attribute__((ext_vector_type(8))) short;
using f32x4  = __attribute__((ext_vector_type(4))) float;

__device__ inline ushort f2bf(float f) {
    __hip_bfloat16 h = __float2bfloat16(f);
    return *reinterpret_cast<ushort*>(&h);
}
__device__ inline float bf2f(ushort u) {
    return __uint_as_float(((unsigned)u) << 16);
}
// Order-preserving float<->uint transform: bitwise atomicMax/Min == float max/min.
__device__ inline unsigned f2ord(float f) {
    unsigned b = __float_as_uint(f);
    return (b & 0x80000000u) ? ~b : (b | 0x80000000u);
}
__device__ inline float ord2f(unsigned u) {
    return __uint_as_float((u & 0x80000000u) ? (u & 0x7FFFFFFFu) : ~u);
}
// Async global->LDS, 16B per lane. LDS dest is wave-uniform base + lane*16.
__device__ inline void ld16_g2l(const void* g, void* l) {
    __builtin_amdgcn_global_load_lds(
        (const __attribute__((address_space(1))) unsigned int*)g,
        (__attribute__((address_space(3))) unsigned int*)l, 16, 0, 0);
}

// ---- workspace layout (bytes) ----
#define XBS_OFF 0u            // 8192*256*2 = 4194304  sorted bf16 rows
#define SQS_OFF 4194304u      // 32768  sorted ||x||^2
#define TGT_OFF 4227072u      // 32768  sorted targets (int)
#define PMX_OFF 4259840u      // 32768  ordered-uint max over positives of (sqc-2acc)
#define NMN_OFF 4292608u      // 32768  ordered-uint min over negatives
#define HST_OFF 4325376u      // 2048   class histogram
#define CNT_OFF 4327424u      // 2048   class scatter cursors
#define TIK_OFF 4329472u      // 4      gram completion ticket
#define BAR_OFF 4329476u      // 4      prep grid-barrier counter
// memset-zeroed region: [HST_OFF, HST_OFF + 4104)

#define PREP_BLOCKS 512

// K1': fused histogram + scan + normalize + scatter.
// 512 blocks x 256 thr (tiny regs/LDS -> trivially all co-resident at 2/CU),
// one device-scope spin barrier between histogram and the rest. hist/cnt2/
// bar/ticket are pre-zeroed by a hipMemsetAsync in kernel_launch.
__global__ __launch_bounds__(256) void prep_kernel(
    const float* __restrict__ in, const int* __restrict__ tgt,
    int* __restrict__ hist, int* __restrict__ cnt2, unsigned* __restrict__ bar,
    ushort* __restrict__ xbs, float* __restrict__ sqs, int* __restrict__ tgts,
    unsigned* __restrict__ pmax, unsigned* __restrict__ nmin)
{
    const int b   = blockIdx.x;
    const int tid = threadIdx.x;

    // Phase A: histogram this block's 16 rows (hist pre-zeroed).
    if (tid < 16) atomicAdd(&hist[tgt[b * 16 + tid]], 1);

    // Grid-wide barrier: all 512 blocks are resident (grid <= capacity),
    // so spinning is deadlock-free. Release on arrival, acquire on spin.
    __threadfence();
    __syncthreads();
    if (tid == 0) {
        __hip_atomic_fetch_add(bar, 1u, __ATOMIC_ACQ_REL, __HIP_MEMORY_SCOPE_AGENT);
        while (__hip_atomic_load(bar, __ATOMIC_ACQUIRE, __HIP_MEMORY_SCOPE_AGENT)
               < (unsigned)PREP_BLOCKS)
            __builtin_amdgcn_s_sleep(2);
    }
    __syncthreads();

    // Phase B: redundant per-block inclusive scan of the 512-class histogram
    // (Hillis-Steele, 256 threads x 2 elems). hist itself stays unmodified,
    // so exclusive base of class t = h[t] - hist[t].
    __shared__ int h[NCLASS];
    h[tid]       = hist[tid];
    h[tid + 256] = hist[tid + 256];
    __syncthreads();
    for (int ofs = 1; ofs < NCLASS; ofs <<= 1) {
        int v0 = (tid >= ofs) ? h[tid - ofs] : 0;
        int v1 = (tid + 256 >= ofs) ? h[tid + 256 - ofs] : 0;
        __syncthreads();
        h[tid]       += v0;
        h[tid + 256] += v1;
        __syncthreads();
    }

    // Phase C: normalize fp32 -> bf16 and scatter to class-sorted slots.
    // One wave per row, 4 sequential rows per wave (identical math to the
    // proven norm_scatter_kernel).
    const int wv   = tid >> 6;
    const int lane = tid & 63;
#pragma unroll 1
    for (int rr = 0; rr < 4; ++rr) {
        int row = b * 16 + wv * 4 + rr;
        float4 v = ((const float4*)(in + (size_t)row * DIM))[lane];
        float ss = v.x * v.x + v.y * v.y + v.z * v.z + v.w * v.w;
#pragma unroll
        for (int m = 1; m < 64; m <<= 1) ss += __shfl_xor(ss, m, 64);
        float inv = 1.0f / (sqrtf(ss) + 1e-12f);

        ushort4 st;
        st.x = f2bf(v.x * inv); st.y = f2bf(v.y * inv);
        st.z = f2bf(v.z * inv); st.w = f2bf(v.w * inv);

        int t = 0, dst = 0;
        if (lane == 0) {
            t = tgt[row];
            dst = (h[t] - hist[t]) + atomicAdd(&cnt2[t], 1);
        }
        dst = __shfl(dst, 0); t = __shfl(t, 0);

        ((ushort4*)(xbs + (size_t)dst * DIM))[lane] = st;

        float a0 = bf2f(st.x), a1 = bf2f(st.y), a2 = bf2f(st.z), a3 = bf2f(st.w);
        float s2 = a0 * a0 + a1 * a1 + a2 * a2 + a3 * a3;
#pragma unroll
        for (int m = 1; m < 64; m <<= 1) s2 += __shfl_xor(s2, m, 64);
        if (lane == 0) {
            sqs[dst]  = s2;
            tgts[dst] = t;
            pmax[dst] = 0x007FFFFFu;  // f2ord(-inf)
            nmin[dst] = 0xFF800000u;  // f2ord(+inf)
        }
    }
}

// K3: fused gram + hard-pos/hard-neg — EXACT round-0 structure (measured
// 46.36us / 740 TF): 4 waves, 256 rows x 512 cols per block, B staged in LDS
// (double-buffered, 32 cols = 16KB per stage) shared by all 4 waves,
// XOR-swizzled for bank-balanced ds_read_b128; prefetch of stage s+1 issued
// at the TOP of stage s so the stage-end barrier drain is ~free. Rounds 2-4
// proved every "improvement" to this structure (L2-direct, private DMA,
// 32-row waves) regresses: 64 rows/wave keeps 4 MFMA per b128 read and the
// 128-reg A-fragment file is the price of that ratio.
// Fused finalize tail (proven R3/R4): last block computes the loss.
__global__ __launch_bounds__(256, 2) void gram_kernel(
    const ushort* __restrict__ xbs, const float* __restrict__ sqs,
    const int* __restrict__ tgts, unsigned* __restrict__ pmax,
    unsigned* __restrict__ nmin, unsigned* __restrict__ ticket,
    float* __restrict__ out)
{
    __shared__ struct {
        char  buf[2][16384];   // B stage buffers: 32 cols x 512B, swizzled
        float sqc[512];        // per-col ||x||^2 for this 512-col chunk
        int   tgc[512];        // per-col class
        int   tga[256];        // per-row class for this block's 256 rows
    } sm;
    __shared__ unsigned lastblk;

    const int wave = threadIdx.x >> 6;
    const int lane = threadIdx.x & 63;
    const int l15  = lane & 15;
    const int quad = lane >> 4;
    const int mbase = blockIdx.x * 256 + wave * 64;
    const int nbase = blockIdx.y * 512;

    // Stage per-chunk metadata into LDS (once).
    {
        int c = threadIdx.x * 2;
        sm.sqc[c]     = sqs[nbase + c];
        sm.sqc[c + 1] = sqs[nbase + c + 1];
        sm.tgc[c]     = tgts[nbase + c];
        sm.tgc[c + 1] = tgts[nbase + c + 1];
        sm.tga[threadIdx.x] = tgts[blockIdx.x * 256 + threadIdx.x];
    }

    // Preload A fragments: 4 tiles x full K=256.
    bf16x8 afrag[4][8];
#pragma unroll
    for (int a = 0; a < 4; ++a) {
        const ushort* arow = xbs + (size_t)(mbase + a * 16 + l15) * DIM + quad * 8;
#pragma unroll
        for (int kk = 0; kk < 8; ++kk)
            afrag[a][kk] = *(const bf16x8*)(arow + kk * 32);
    }
    const int rlo = tgts[mbase];       // sorted => wave row-class range
    const int rhi = tgts[mbase + 63];

    // Per-lane global source offsets for staging (xor-swizzle compensation).
    // Stage instr i writes LDS [i*1024,(i+1)*1024): col=2i+(lane>>5), slot=lane&31,
    // which must hold logical chunk c = slot ^ (col&7).
    const int colh = lane >> 5, c31 = lane & 31;
    int offs[4];
#pragma unroll
    for (int j = 0; j < 4; ++j)
        offs[j] = colh * 512 + ((c31 ^ ((2 * j + colh) & 7)) << 4);

    const char* xbs_b = (const char*)xbs;

    // Prologue: issue stage 0.
    {
        const char* gbase = xbs_b + (size_t)nbase * 512;
#pragma unroll
        for (int j = 0; j < 4; ++j) {
            int i = wave * 4 + j;
            ld16_g2l(gbase + i * 1024 + offs[j], sm.buf[0] + i * 1024);
        }
    }
    __syncthreads();  // drains prologue DMA + metadata writes

    float pm[16], nm[16];
#pragma unroll
    for (int j = 0; j < 16; ++j) { pm[j] = -__builtin_inff(); nm[j] = __builtin_inff(); }

#pragma unroll 2
    for (int s = 0; s < 16; ++s) {
        // Issue stage s+1 into the other buffer (free: everyone done reading it).
        if (s < 15) {
            const char* gbase = xbs_b + (size_t)(nbase + (s + 1) * 32) * 512;
            char* lbase = sm.buf[(s + 1) & 1];
#pragma unroll
            for (int j = 0; j < 4; ++j) {
                int i = wave * 4 + j;
                ld16_g2l(gbase + i * 1024 + offs[j], lbase + i * 1024);
            }
        }
        // Compute the two 16-col tiles of the current buffer.
        const char* bufc = sm.buf[s & 1];
#pragma unroll
        for (int u = 0; u < 2; ++u) {
            const int t16 = s * 32 + u * 16;
            bf16x8 bfrag[8];
#pragma unroll
            for (int kk = 0; kk < 8; ++kk)
                bfrag[kk] = *(const bf16x8*)(bufc + u * 8192 + l15 * 512 +
                                             (((quad + 4 * kk) ^ (l15 & 7)) << 4));
            f32x4 acc4[4];
#pragma unroll
            for (int a = 0; a < 4; ++a) {
                f32x4 acc = {0.f, 0.f, 0.f, 0.f};
#pragma unroll
                for (int kk = 0; kk < 8; ++kk)
                    acc = __builtin_amdgcn_mfma_f32_16x16x32_bf16(afrag[a][kk], bfrag[kk], acc, 0, 0, 0);
                acc4[a] = acc;
            }
            const float sqc = sm.sqc[t16 + l15];
            const int clo = sm.tgc[t16], chi = sm.tgc[t16 + 15];
            if (rlo <= chi && clo <= rhi) {
                // slow path: tile may contain positives
                const int tc = sm.tgc[t16 + l15];
#pragma unroll
                for (int a = 0; a < 4; ++a)
#pragma unroll
                    for (int i = 0; i < 4; ++i) {
                        const float v = fmaf(acc4[a][i], -2.0f, sqc);
                        const bool same = (sm.tga[wave * 64 + a * 16 + quad * 4 + i] == tc);
                        pm[a * 4 + i] = fmaxf(pm[a * 4 + i], same ? v : -__builtin_inff());
                        nm[a * 4 + i] = fminf(nm[a * 4 + i], same ? __builtin_inff() : v);
                    }
            } else {
                // fast path: negatives only
#pragma unroll
                for (int a = 0; a < 4; ++a)
#pragma unroll
                    for (int i = 0; i < 4; ++i)
                        nm[a * 4 + i] = fminf(nm[a * 4 + i], fmaf(acc4[a][i], -2.0f, sqc));
            }
        }
        __syncthreads();  // stage-s+1 DMA landed long ago -> drain is ~free
    }

    // Reduce across the 16 column-lanes (same quad), then one atomic per row.
#pragma unroll
    for (int m = 1; m < 16; m <<= 1) {
#pragma unroll
        for (int j = 0; j < 16; ++j) {
            pm[j] = fmaxf(pm[j], __shfl_xor(pm[j], m, 64));
            nm[j] = fminf(nm[j], __shfl_xor(nm[j], m, 64));
        }
    }
    if (l15 == 0) {
#pragma unroll
        for (int a = 0; a < 4; ++a)
#pragma unroll
            for (int i = 0; i < 4; ++i) {
                int r = mbase + a * 16 + quad * 4 + i;
                atomicMax(&pmax[r], f2ord(pm[a * 4 + i]));
                atomicMin(&nmin[r], f2ord(nm[a * 4 + i]));
            }
    }

    // ---- fused finalize: last block to finish computes the loss ----
    __threadfence();
    if (threadIdx.x == 0)
        lastblk = (atomicAdd(ticket, 1u) == 511u) ? 1u : 0u;
    __syncthreads();
    if (lastblk) {
        __threadfence();  // acquire: all blocks' pmax/nmin RMWs precede ticket==511
        double s = 0.0;
        for (int r = threadIdx.x; r < NROWS; r += 256) {
            unsigned pu = __hip_atomic_load(&pmax[r], __ATOMIC_RELAXED,
                                            __HIP_MEMORY_SCOPE_AGENT);
            unsigned nu = __hip_atomic_load(&nmin[r], __ATOMIC_RELAXED,
                                            __HIP_MEMORY_SCOPE_AGENT);
            float pe = ord2f(pu);
            float ne = ord2f(nu);
            float ap = sqrtf(fmaxf(sqs[r] + pe, 0.0f));
            float an = (ne > 1e30f) ? (MARGIN + 1.0f) : sqrtf(fmaxf(sqs[r] + ne, 0.0f));
            s += (double)fmaxf(ap - an + MARGIN, 0.0f);
        }
#pragma unroll
        for (int m = 1; m < 64; m <<= 1) s += __shfl_xor(s, m, 64);
        __shared__ double sh[4];
        if ((threadIdx.x & 63) == 0) sh[threadIdx.x >> 6] = s;
        __syncthreads();
        if (threadIdx.x == 0)
            out[0] = (float)((sh[0] + sh[1] + sh[2] + sh[3]) / (double)NROWS);
    }
}

extern "C" void kernel_launch(void* const* d_in, const int* in_sizes, int n_in,
                              void* d_out, int out_size, void* d_ws, size_t ws_size,
                              hipStream_t stream) {
    const float* in  = (const float*)d_in[0];
    const int*   tgt = (const int*)d_in[1];
    float*       out = (float*)d_out;

    char* ws = (char*)d_ws;
    ushort*   xbs    = (ushort*)(ws + XBS_OFF);
    float*    sqs    = (float*)(ws + SQS_OFF);
    int*      tgts   = (int*)(ws + TGT_OFF);
    unsigned* pmax   = (unsigned*)(ws + PMX_OFF);
    unsigned* nmin   = (unsigned*)(ws + NMN_OFF);
    int*      hist   = (int*)(ws + HST_OFF);
    int*      cnt2   = (int*)(ws + CNT_OFF);
    unsigned* ticket = (unsigned*)(ws + TIK_OFF);
    unsigned* bar    = (unsigned*)(ws + BAR_OFF);

    // Zero hist + cnt2 + ticket + bar in one async memset (graph-capture-safe).
    hipMemsetAsync(ws + HST_OFF, 0, 4104, stream);
    prep_kernel<<<PREP_BLOCKS, 256, 0, stream>>>(in, tgt, hist, cnt2, bar,
                                                 xbs, sqs, tgts, pmax, nmin);
    gram_kernel<<<dim3(32, 16), 256, 0, stream>>>(xbs, sqs, tgts, pmax, nmin,
                                                  ticket, out);
}

// Round 6
// 122.312 us; speedup vs baseline: 1.5638x; 1.5638x over previous
//
#include <hip/hip_runtime.h>
#include <hip/hip_bf16.h>

#define NROWS  8192
#define DIM    256
#define NCLASS 512
#define MARGIN 0.3f

using bf16x8 = __attribute__((ext_vector_type(8))) short;
using f32x4  = __attribute__((ext_vector_type(4))) float;

__device__ inline ushort f2bf(float f) {
    __hip_bfloat16 h = __float2bfloat16(f);
    return *reinterpret_cast<ushort*>(&h);
}
__device__ inline float bf2f(ushort u) {
    return __uint_as_float(((unsigned)u) << 16);
}
// Order-preserving float<->uint transform: bitwise atomicMax/Min == float max/min.
__device__ inline unsigned f2ord(float f) {
    unsigned b = __float_as_uint(f);
    return (b & 0x80000000u) ? ~b : (b | 0x80000000u);
}
__device__ inline float ord2f(unsigned u) {
    return __uint_as_float((u & 0x80000000u) ? (u & 0x7FFFFFFFu) : ~u);
}
// Async global->LDS, 16B per lane. LDS dest is wave-uniform base + lane*16.
__device__ inline void ld16_g2l(const void* g, void* l) {
    __builtin_amdgcn_global_load_lds(
        (const __attribute__((address_space(1))) unsigned int*)g,
        (__attribute__((address_space(3))) unsigned int*)l, 16, 0, 0);
}

// ---- workspace layout (bytes) ----
#define XBS_OFF 0u            // 8192*256*2 = 4194304  sorted bf16 rows
#define SQS_OFF 4194304u      // 32768  sorted ||x||^2
#define TGT_OFF 4227072u      // 32768  sorted targets (int)
#define PMX_OFF 4259840u      // 32768  ordered-uint max over positives of (sqc-2acc)
#define NMN_OFF 4292608u      // 32768  ordered-uint min over negatives
#define CNT_OFF 4325376u      // 2048   class scatter cursors
#define ACC_OFF 4327424u      // 8      double loss accumulator
#define TIK_OFF 4327432u      // 4      finalize completion ticket
// memset-zeroed region: [CNT_OFF, CNT_OFF + 2060)

// K2': fence-free fused histogram + scan + normalize + scatter.
// 512 blocks x 256 thr, 16 rows each. EVERY block redundantly computes the
// full 512-class histogram (reads all 8192 targets, 32KB, L2-broadcast after
// the first block) and scans it in LDS -- identical bases in every block, so
// no grid barrier and NO device-scope fences (R5's spin-barrier fusion cost
// ~95us: every acquire poll invalidates the XCD L2). Only cross-block state
// is the per-class cursor atomicAdd (proven cheap in R0's bincur).
// Scan + scatter code is R5's prep (verified absmax 0).
__global__ __launch_bounds__(256) void prep_kernel(
    const float* __restrict__ in, const int* __restrict__ tgt,
    int* __restrict__ cnt2, ushort* __restrict__ xbs,
    float* __restrict__ sqs, int* __restrict__ tgts,
    unsigned* __restrict__ pmax, unsigned* __restrict__ nmin)
{
    __shared__ int hcnt[NCLASS];   // raw per-class counts (local)
    __shared__ int h[NCLASS];      // inclusive scan (local)
    const int b   = blockIdx.x;
    const int tid = threadIdx.x;

    hcnt[tid] = 0; hcnt[tid + 256] = 0;
    __syncthreads();
    // Local histogram of ALL 8192 targets (coalesced, 32 per thread).
#pragma unroll 4
    for (int k = 0; k < NROWS / 256; ++k)
        atomicAdd(&hcnt[tgt[tid + k * 256]], 1);
    __syncthreads();
    h[tid] = hcnt[tid]; h[tid + 256] = hcnt[tid + 256];
    __syncthreads();
    // Inclusive Hillis-Steele scan over 512 classes, 2 elems/thread.
    for (int ofs = 1; ofs < NCLASS; ofs <<= 1) {
        int v0 = (tid >= ofs) ? h[tid - ofs] : 0;
        int v1 = (tid + 256 >= ofs) ? h[tid + 256 - ofs] : 0;
        __syncthreads();
        h[tid]       += v0;
        h[tid + 256] += v1;
        __syncthreads();
    }
    // exclusive base of class t = h[t] - hcnt[t]

    // Normalize fp32 -> bf16 and scatter this block's 16 rows to class-sorted
    // slots. One wave per row, 4 sequential rows per wave (proven R0 math).
    const int wv   = tid >> 6;
    const int lane = tid & 63;
#pragma unroll 1
    for (int rr = 0; rr < 4; ++rr) {
        int row = b * 16 + wv * 4 + rr;
        float4 v = ((const float4*)(in + (size_t)row * DIM))[lane];
        float ss = v.x * v.x + v.y * v.y + v.z * v.z + v.w * v.w;
#pragma unroll
        for (int m = 1; m < 64; m <<= 1) ss += __shfl_xor(ss, m, 64);
        float inv = 1.0f / (sqrtf(ss) + 1e-12f);

        ushort4 st;
        st.x = f2bf(v.x * inv); st.y = f2bf(v.y * inv);
        st.z = f2bf(v.z * inv); st.w = f2bf(v.w * inv);

        int t = 0, dst = 0;
        if (lane == 0) {
            t = tgt[row];
            dst = (h[t] - hcnt[t]) + atomicAdd(&cnt2[t], 1);
        }
        dst = __shfl(dst, 0); t = __shfl(t, 0);

        ((ushort4*)(xbs + (size_t)dst * DIM))[lane] = st;

        float a0 = bf2f(st.x), a1 = bf2f(st.y), a2 = bf2f(st.z), a3 = bf2f(st.w);
        float s2 = a0 * a0 + a1 * a1 + a2 * a2 + a3 * a3;
#pragma unroll
        for (int m = 1; m < 64; m <<= 1) s2 += __shfl_xor(s2, m, 64);
        if (lane == 0) {
            sqs[dst]  = s2;
            tgts[dst] = t;
            pmax[dst] = 0x007FFFFFu;  // f2ord(-inf)
            nmin[dst] = 0xFF800000u;  // f2ord(+inf)
        }
    }
}

// K3: fused gram + hard-pos/hard-neg. BYTE-EXACT round-0 kernel (measured
// 46.36us, MfmaUtil 28.9%): 4 waves, 256 rows x 512 cols, B staged in LDS
// (double-buffered, 32 cols = 16KB per stage) shared by all 4 waves,
// XOR-swizzled for bank-balanced ds_read_b128; stage s+1 prefetch issued at
// the TOP of stage s. NO fused tail: R5 measured the per-block
// __threadfence() + ticket tail at ~+37us (device-scope fence = L2
// writeback/invalidate across 8 non-coherent XCDs).
__global__ __launch_bounds__(256, 2) void gram_kernel(
    const ushort* __restrict__ xbs, const float* __restrict__ sqs,
    const int* __restrict__ tgts, unsigned* __restrict__ pmax,
    unsigned* __restrict__ nmin)
{
    __shared__ struct {
        char  buf[2][16384];   // B stage buffers: 32 cols x 512B, swizzled
        float sqc[512];        // per-col ||x||^2 for this 512-col chunk
        int   tgc[512];        // per-col class
        int   tga[256];        // per-row class for this block's 256 rows
    } sm;

    const int wave = threadIdx.x >> 6;
    const int lane = threadIdx.x & 63;
    const int l15  = lane & 15;
    const int quad = lane >> 4;
    const int mbase = blockIdx.x * 256 + wave * 64;
    const int nbase = blockIdx.y * 512;

    // Stage per-chunk metadata into LDS (once).
    {
        int c = threadIdx.x * 2;
        sm.sqc[c]     = sqs[nbase + c];
        sm.sqc[c + 1] = sqs[nbase + c + 1];
        sm.tgc[c]     = tgts[nbase + c];
        sm.tgc[c + 1] = tgts[nbase + c + 1];
        sm.tga[threadIdx.x] = tgts[blockIdx.x * 256 + threadIdx.x];
    }

    // Preload A fragments: 4 tiles x full K=256.
    bf16x8 afrag[4][8];
#pragma unroll
    for (int a = 0; a < 4; ++a) {
        const ushort* arow = xbs + (size_t)(mbase + a * 16 + l15) * DIM + quad * 8;
#pragma unroll
        for (int kk = 0; kk < 8; ++kk)
            afrag[a][kk] = *(const bf16x8*)(arow + kk * 32);
    }
    const int rlo = tgts[mbase];       // sorted => wave row-class range
    const int rhi = tgts[mbase + 63];

    // Per-lane global source offsets for staging (xor-swizzle compensation).
    // Stage instr i writes LDS [i*1024,(i+1)*1024): col=2i+(lane>>5), slot=lane&31,
    // which must hold logical chunk c = slot ^ (col&7).
    const int colh = lane >> 5, c31 = lane & 31;
    int offs[4];
#pragma unroll
    for (int j = 0; j < 4; ++j)
        offs[j] = colh * 512 + ((c31 ^ ((2 * j + colh) & 7)) << 4);

    const char* xbs_b = (const char*)xbs;

    // Prologue: issue stage 0.
    {
        const char* gbase = xbs_b + (size_t)nbase * 512;
#pragma unroll
        for (int j = 0; j < 4; ++j) {
            int i = wave * 4 + j;
            ld16_g2l(gbase + i * 1024 + offs[j], sm.buf[0] + i * 1024);
        }
    }
    __syncthreads();  // drains prologue DMA + metadata writes

    float pm[16], nm[16];
#pragma unroll
    for (int j = 0; j < 16; ++j) { pm[j] = -__builtin_inff(); nm[j] = __builtin_inff(); }

#pragma unroll 2
    for (int s = 0; s < 16; ++s) {
        // Issue stage s+1 into the other buffer (free: everyone done reading it).
        if (s < 15) {
            const char* gbase = xbs_b + (size_t)(nbase + (s + 1) * 32) * 512;
            char* lbase = sm.buf[(s + 1) & 1];
#pragma unroll
            for (int j = 0; j < 4; ++j) {
                int i = wave * 4 + j;
                ld16_g2l(gbase + i * 1024 + offs[j], lbase + i * 1024);
            }
        }
        // Compute the two 16-col tiles of the current buffer.
        const char* bufc = sm.buf[s & 1];
#pragma unroll
        for (int u = 0; u < 2; ++u) {
            const int t16 = s * 32 + u * 16;
            bf16x8 bfrag[8];
#pragma unroll
            for (int kk = 0; kk < 8; ++kk)
                bfrag[kk] = *(const bf16x8*)(bufc + u * 8192 + l15 * 512 +
                                             (((quad + 4 * kk) ^ (l15 & 7)) << 4));
            f32x4 acc4[4];
#pragma unroll
            for (int a = 0; a < 4; ++a) {
                f32x4 acc = {0.f, 0.f, 0.f, 0.f};
#pragma unroll
                for (int kk = 0; kk < 8; ++kk)
                    acc = __builtin_amdgcn_mfma_f32_16x16x32_bf16(afrag[a][kk], bfrag[kk], acc, 0, 0, 0);
                acc4[a] = acc;
            }
            const float sqc = sm.sqc[t16 + l15];
            const int clo = sm.tgc[t16], chi = sm.tgc[t16 + 15];
            if (rlo <= chi && clo <= rhi) {
                // slow path: tile may contain positives
                const int tc = sm.tgc[t16 + l15];
#pragma unroll
                for (int a = 0; a < 4; ++a)
#pragma unroll
                    for (int i = 0; i < 4; ++i) {
                        const float v = fmaf(acc4[a][i], -2.0f, sqc);
                        const bool same = (sm.tga[wave * 64 + a * 16 + quad * 4 + i] == tc);
                        pm[a * 4 + i] = fmaxf(pm[a * 4 + i], same ? v : -__builtin_inff());
                        nm[a * 4 + i] = fminf(nm[a * 4 + i], same ? __builtin_inff() : v);
                    }
            } else {
                // fast path: negatives only
#pragma unroll
                for (int a = 0; a < 4; ++a)
#pragma unroll
                    for (int i = 0; i < 4; ++i)
                        nm[a * 4 + i] = fminf(nm[a * 4 + i], fmaf(acc4[a][i], -2.0f, sqc));
            }
        }
        __syncthreads();  // stage-s+1 DMA landed long ago -> drain is ~free
    }

    // Reduce across the 16 column-lanes (same quad), then one atomic per row.
#pragma unroll
    for (int m = 1; m < 16; m <<= 1) {
#pragma unroll
        for (int j = 0; j < 16; ++j) {
            pm[j] = fmaxf(pm[j], __shfl_xor(pm[j], m, 64));
            nm[j] = fminf(nm[j], __shfl_xor(nm[j], m, 64));
        }
    }
    if (l15 == 0) {
#pragma unroll
        for (int a = 0; a < 4; ++a)
#pragma unroll
            for (int i = 0; i < 4; ++i) {
                int r = mbase + a * 16 + quad * 4 + i;
                atomicMax(&pmax[r], f2ord(pm[a * 4 + i]));
                atomicMin(&nmin[r], f2ord(nm[a * 4 + i]));
            }
    }
}

// K4: multi-block finalize with fp64 atomic accumulation + completion ticket
// (byte-exact round-0 version; accd/ticket pre-zeroed by the memset).
__global__ __launch_bounds__(256) void finalize_kernel(
    const unsigned* __restrict__ pmax, const unsigned* __restrict__ nmin,
    const float* __restrict__ sqs, double* __restrict__ accd,
    unsigned* __restrict__ ticket, float* __restrict__ out)
{
    int r = blockIdx.x * 256 + threadIdx.x;
    float pe = ord2f(pmax[r]);
    float ne = ord2f(nmin[r]);
    float ap = sqrtf(fmaxf(sqs[r] + pe, 0.0f));
    float an = (ne > 1e30f) ? (MARGIN + 1.0f) : sqrtf(fmaxf(sqs[r] + ne, 0.0f));
    float h  = fmaxf(ap - an + MARGIN, 0.0f);
    double s = (double)h;
#pragma unroll
    for (int m = 1; m < 64; m <<= 1) s += __shfl_xor(s, m, 64);
    __shared__ double sh[4];
    if ((threadIdx.x & 63) == 0) sh[threadIdx.x >> 6] = s;
    __syncthreads();
    if (threadIdx.x == 0) {
        double b = sh[0] + sh[1] + sh[2] + sh[3];
        atomicAdd(accd, b);
        __threadfence();
        unsigned old = atomicAdd(ticket, 1u);
        if (old == gridDim.x - 1) {
            double total = atomicAdd(accd, 0.0);  // coherent read
            out[0] = (float)(total / (double)NROWS);
        }
    }
}

extern "C" void kernel_launch(void* const* d_in, const int* in_sizes, int n_in,
                              void* d_out, int out_size, void* d_ws, size_t ws_size,
                              hipStream_t stream) {
    const float* in  = (const float*)d_in[0];
    const int*   tgt = (const int*)d_in[1];
    float*       out = (float*)d_out;

    char* ws = (char*)d_ws;
    ushort*   xbs    = (ushort*)(ws + XBS_OFF);
    float*    sqs    = (float*)(ws + SQS_OFF);
    int*      tgts   = (int*)(ws + TGT_OFF);
    unsigned* pmax   = (unsigned*)(ws + PMX_OFF);
    unsigned* nmin   = (unsigned*)(ws + NMN_OFF);
    int*      cnt2   = (int*)(ws + CNT_OFF);
    double*   accd   = (double*)(ws + ACC_OFF);
    unsigned* ticket = (unsigned*)(ws + TIK_OFF);

    // Zero cnt2 + accd + ticket in one small async memset (graph-capture-safe).
    hipMemsetAsync(ws + CNT_OFF, 0, 2060, stream);
    prep_kernel<<<512, 256, 0, stream>>>(in, tgt, cnt2, xbs, sqs, tgts, pmax, nmin);
    gram_kernel<<<dim3(32, 16), 256, 0, stream>>>(xbs, sqs, tgts, pmax, nmin);
    finalize_kernel<<<32, 256, 0, stream>>>(pmax, nmin, sqs, accd, ticket, out);
}

// Round 7
// 108.617 us; speedup vs baseline: 1.7610x; 1.1261x over previous
//
#include <hip/hip_runtime.h>
#include <hip/hip_bf16.h>

#define NROWS  8192
#define DIM    256
#define MARGIN 0.3f

using bf16x8 = __attribute__((ext_vector_type(8))) short;
using f32x4  = __attribute__((ext_vector_type(4))) float;

__device__ inline ushort f2bf(float f) {
    __hip_bfloat16 h = __float2bfloat16(f);
    return *reinterpret_cast<ushort*>(&h);
}
__device__ inline float bf2f(ushort u) {
    return __uint_as_float(((unsigned)u) << 16);
}
// Order-preserving float<->uint transform: bitwise atomicMax/Min == float max/min.
__device__ inline unsigned f2ord(float f) {
    unsigned b = __float_as_uint(f);
    return (b & 0x80000000u) ? ~b : (b | 0x80000000u);
}
__device__ inline float ord2f(unsigned u) {
    return __uint_as_float((u & 0x80000000u) ? (u & 0x7FFFFFFFu) : ~u);
}
// Async global->LDS, 16B per lane. LDS dest is wave-uniform base + lane*16.
__device__ inline void ld16_g2l(const void* g, void* l) {
    __builtin_amdgcn_global_load_lds(
        (const __attribute__((address_space(1))) unsigned int*)g,
        (__attribute__((address_space(3))) unsigned int*)l, 16, 0, 0);
}

// ---- workspace layout (bytes) ----
// NO SORT this round: rows stay in input order. The class-sort only fed
// gram's fast-path gating (~2.6us of VALU); it cost a serial single-block
// hist_scan kernel + scatter atomics + one dispatch boundary (~8-12us).
#define XBS_OFF 0u            // 8192*256*2 = 4194304  normalized bf16 rows (input order)
#define SQS_OFF 4194304u      // 32768  ||x||^2 per row
#define PMX_OFF 4259840u      // 32768  ordered-uint max over positives of (sqc-2acc)
#define NMN_OFF 4292608u      // 32768  ordered-uint min over negatives
#define ACC_OFF 4327424u      // 8      double loss accumulator
#define TIK_OFF 4327432u      // 4      finalize completion ticket

// K1: one wave per row. Normalize fp32 -> bf16 IN PLACE (no scatter/sort).
// Block 0 thread 0 also zeroes the finalize accumulator+ticket (visible to
// finalize via stream order -- no fences needed; R5 proved device-scope
// fences in hot kernels cost ~37us+).
__global__ __launch_bounds__(256) void norm_kernel(
    const float* __restrict__ in, ushort* __restrict__ xbs,
    float* __restrict__ sqs, unsigned* __restrict__ pmax,
    unsigned* __restrict__ nmin, double* __restrict__ accd,
    unsigned* __restrict__ ticket)
{
    int row  = blockIdx.x * 4 + (threadIdx.x >> 6);
    int lane = threadIdx.x & 63;
    if (blockIdx.x == 0 && threadIdx.x == 0) { *accd = 0.0; *ticket = 0u; }
    float4 v = ((const float4*)(in + (size_t)row * DIM))[lane];
    float ss = v.x * v.x + v.y * v.y + v.z * v.z + v.w * v.w;
#pragma unroll
    for (int m = 1; m < 64; m <<= 1) ss += __shfl_xor(ss, m, 64);
    float inv = 1.0f / (sqrtf(ss) + 1e-12f);

    ushort4 st;
    st.x = f2bf(v.x * inv); st.y = f2bf(v.y * inv);
    st.z = f2bf(v.z * inv); st.w = f2bf(v.w * inv);

    ((ushort4*)(xbs + (size_t)row * DIM))[lane] = st;

    float a0 = bf2f(st.x), a1 = bf2f(st.y), a2 = bf2f(st.z), a3 = bf2f(st.w);
    float s2 = a0 * a0 + a1 * a1 + a2 * a2 + a3 * a3;
#pragma unroll
    for (int m = 1; m < 64; m <<= 1) s2 += __shfl_xor(s2, m, 64);
    if (lane == 0) {
        sqs[row]  = s2;
        pmax[row] = 0x007FFFFFu;  // f2ord(-inf)
        nmin[row] = 0xFF800000u;  // f2ord(+inf)
    }
}

// K2: fused gram + hard-pos/hard-neg. Inner loop BYTE-IDENTICAL to the
// measured-47.4us round-0 kernel (4 waves, 256 rows x 512 cols, shared
// double-buffered LDS B staging, XOR-swizzle pair, stage-s+1 prefetch at
// stage-s top, per-stage __syncthreads). Only delta: rows are unsorted, so
// the fast-path class-range gate is gone -- every tile runs the slow-path
// epilogue (tga/tgc compare, ~+2.6us VALU). tgc/tga read straight from tgt.
__global__ __launch_bounds__(256, 2) void gram_kernel(
    const ushort* __restrict__ xbs, const float* __restrict__ sqs,
    const int* __restrict__ tgt, unsigned* __restrict__ pmax,
    unsigned* __restrict__ nmin)
{
    __shared__ struct {
        char  buf[2][16384];   // B stage buffers: 32 cols x 512B, swizzled
        float sqc[512];        // per-col ||x||^2 for this 512-col chunk
        int   tgc[512];        // per-col class
        int   tga[256];        // per-row class for this block's 256 rows
    } sm;

    const int wave = threadIdx.x >> 6;
    const int lane = threadIdx.x & 63;
    const int l15  = lane & 15;
    const int quad = lane >> 4;
    const int mbase = blockIdx.x * 256 + wave * 64;
    const int nbase = blockIdx.y * 512;

    // Stage per-chunk metadata into LDS (once).
    {
        int c = threadIdx.x * 2;
        sm.sqc[c]     = sqs[nbase + c];
        sm.sqc[c + 1] = sqs[nbase + c + 1];
        sm.tgc[c]     = tgt[nbase + c];
        sm.tgc[c + 1] = tgt[nbase + c + 1];
        sm.tga[threadIdx.x] = tgt[blockIdx.x * 256 + threadIdx.x];
    }

    // Preload A fragments: 4 tiles x full K=256.
    bf16x8 afrag[4][8];
#pragma unroll
    for (int a = 0; a < 4; ++a) {
        const ushort* arow = xbs + (size_t)(mbase + a * 16 + l15) * DIM + quad * 8;
#pragma unroll
        for (int kk = 0; kk < 8; ++kk)
            afrag[a][kk] = *(const bf16x8*)(arow + kk * 32);
    }

    // Per-lane global source offsets for staging (xor-swizzle compensation).
    // Stage instr i writes LDS [i*1024,(i+1)*1024): col=2i+(lane>>5), slot=lane&31,
    // which must hold logical chunk c = slot ^ (col&7).
    const int colh = lane >> 5, c31 = lane & 31;
    int offs[4];
#pragma unroll
    for (int j = 0; j < 4; ++j)
        offs[j] = colh * 512 + ((c31 ^ ((2 * j + colh) & 7)) << 4);

    const char* xbs_b = (const char*)xbs;

    // Prologue: issue stage 0.
    {
        const char* gbase = xbs_b + (size_t)nbase * 512;
#pragma unroll
        for (int j = 0; j < 4; ++j) {
            int i = wave * 4 + j;
            ld16_g2l(gbase + i * 1024 + offs[j], sm.buf[0] + i * 1024);
        }
    }
    __syncthreads();  // drains prologue DMA + metadata writes

    float pm[16], nm[16];
#pragma unroll
    for (int j = 0; j < 16; ++j) { pm[j] = -__builtin_inff(); nm[j] = __builtin_inff(); }

#pragma unroll 2
    for (int s = 0; s < 16; ++s) {
        // Issue stage s+1 into the other buffer (free: everyone done reading it).
        if (s < 15) {
            const char* gbase = xbs_b + (size_t)(nbase + (s + 1) * 32) * 512;
            char* lbase = sm.buf[(s + 1) & 1];
#pragma unroll
            for (int j = 0; j < 4; ++j) {
                int i = wave * 4 + j;
                ld16_g2l(gbase + i * 1024 + offs[j], lbase + i * 1024);
            }
        }
        // Compute the two 16-col tiles of the current buffer.
        const char* bufc = sm.buf[s & 1];
#pragma unroll
        for (int u = 0; u < 2; ++u) {
            const int t16 = s * 32 + u * 16;
            bf16x8 bfrag[8];
#pragma unroll
            for (int kk = 0; kk < 8; ++kk)
                bfrag[kk] = *(const bf16x8*)(bufc + u * 8192 + l15 * 512 +
                                             (((quad + 4 * kk) ^ (l15 & 7)) << 4));
            f32x4 acc4[4];
#pragma unroll
            for (int a = 0; a < 4; ++a) {
                f32x4 acc = {0.f, 0.f, 0.f, 0.f};
#pragma unroll
                for (int kk = 0; kk < 8; ++kk)
                    acc = __builtin_amdgcn_mfma_f32_16x16x32_bf16(afrag[a][kk], bfrag[kk], acc, 0, 0, 0);
                acc4[a] = acc;
            }
            const float sqc = sm.sqc[t16 + l15];
            const int   tc  = sm.tgc[t16 + l15];
#pragma unroll
            for (int a = 0; a < 4; ++a)
#pragma unroll
                for (int i = 0; i < 4; ++i) {
                    const float v = fmaf(acc4[a][i], -2.0f, sqc);
                    const bool same = (sm.tga[wave * 64 + a * 16 + quad * 4 + i] == tc);
                    pm[a * 4 + i] = fmaxf(pm[a * 4 + i], same ? v : -__builtin_inff());
                    nm[a * 4 + i] = fminf(nm[a * 4 + i], same ? __builtin_inff() : v);
                }
        }
        __syncthreads();  // stage-s+1 DMA landed long ago -> drain is ~free
    }

    // Reduce across the 16 column-lanes (same quad), then one atomic per row.
#pragma unroll
    for (int m = 1; m < 16; m <<= 1) {
#pragma unroll
        for (int j = 0; j < 16; ++j) {
            pm[j] = fmaxf(pm[j], __shfl_xor(pm[j], m, 64));
            nm[j] = fminf(nm[j], __shfl_xor(nm[j], m, 64));
        }
    }
    if (l15 == 0) {
#pragma unroll
        for (int a = 0; a < 4; ++a)
#pragma unroll
            for (int i = 0; i < 4; ++i) {
                int r = mbase + a * 16 + quad * 4 + i;
                atomicMax(&pmax[r], f2ord(pm[a * 4 + i]));
                atomicMin(&nmin[r], f2ord(nm[a * 4 + i]));
            }
    }
}

// K3: multi-block finalize with fp64 atomic accumulation + completion ticket
// (byte-exact round-0 version; accd/ticket zeroed by norm_kernel).
// Self-pair is included as a "positive" (d2_self ~ 0, never wins unless the
// class is a singleton, where ap ~ 0 matches the reference fallback).
__global__ __launch_bounds__(256) void finalize_kernel(
    const unsigned* __restrict__ pmax, const unsigned* __restrict__ nmin,
    const float* __restrict__ sqs, double* __restrict__ accd,
    unsigned* __restrict__ ticket, float* __restrict__ out)
{
    int r = blockIdx.x * 256 + threadIdx.x;
    float pe = ord2f(pmax[r]);
    float ne = ord2f(nmin[r]);
    float ap = sqrtf(fmaxf(sqs[r] + pe, 0.0f));
    float an = (ne > 1e30f) ? (MARGIN + 1.0f) : sqrtf(fmaxf(sqs[r] + ne, 0.0f));
    float h  = fmaxf(ap - an + MARGIN, 0.0f);
    double s = (double)h;
#pragma unroll
    for (int m = 1; m < 64; m <<= 1) s += __shfl_xor(s, m, 64);
    __shared__ double sh[4];
    if ((threadIdx.x & 63) == 0) sh[threadIdx.x >> 6] = s;
    __syncthreads();
    if (threadIdx.x == 0) {
        double b = sh[0] + sh[1] + sh[2] + sh[3];
        atomicAdd(accd, b);
        __threadfence();
        unsigned old = atomicAdd(ticket, 1u);
        if (old == gridDim.x - 1) {
            double total = atomicAdd(accd, 0.0);  // coherent read
            out[0] = (float)(total / (double)NROWS);
        }
    }
}

extern "C" void kernel_launch(void* const* d_in, const int* in_sizes, int n_in,
                              void* d_out, int out_size, void* d_ws, size_t ws_size,
                              hipStream_t stream) {
    const float* in  = (const float*)d_in[0];
    const int*   tgt = (const int*)d_in[1];
    float*       out = (float*)d_out;

    char* ws = (char*)d_ws;
    ushort*   xbs    = (ushort*)(ws + XBS_OFF);
    float*    sqs    = (float*)(ws + SQS_OFF);
    unsigned* pmax   = (unsigned*)(ws + PMX_OFF);
    unsigned* nmin   = (unsigned*)(ws + NMN_OFF);
    double*   accd   = (double*)(ws + ACC_OFF);
    unsigned* ticket = (unsigned*)(ws + TIK_OFF);

    norm_kernel<<<NROWS / 4, 256, 0, stream>>>(in, xbs, sqs, pmax, nmin, accd, ticket);
    gram_kernel<<<dim3(32, 16), 256, 0, stream>>>(xbs, sqs, tgt, pmax, nmin);
    finalize_kernel<<<32, 256, 0, stream>>>(pmax, nmin, sqs, accd, ticket, out);
}